// Round 1
// baseline (3218.596 us; speedup 1.0000x reference)
//
#include <hip/hip_runtime.h>

#define V_N    20000
#define NNZ_N  640000
#define B_N    16
#define CIN_N  128
#define COUT_N 128
#define F_N    2048   // B*CIN = features per vertex

// ---------------------------------------------------------------------------
// Tiled 2D transpose: in (R x C) row-major -> out (C x R) row-major.
// ---------------------------------------------------------------------------
__global__ __launch_bounds__(256) void k_transpose(const float* __restrict__ in,
                                                   float* __restrict__ out,
                                                   int R, int C)
{
    __shared__ float tile[32][33];
    int cb = blockIdx.x * 32;
    int rb = blockIdx.y * 32;
    int tx = threadIdx.x;   // 0..31
    int ty = threadIdx.y;   // 0..7
#pragma unroll
    for (int j = 0; j < 4; ++j) {
        int r = rb + ty + j * 8, c = cb + tx;
        if (r < R && c < C) tile[ty + j * 8][tx] = in[(size_t)r * C + c];
    }
    __syncthreads();
#pragma unroll
    for (int j = 0; j < 4; ++j) {
        int c = cb + ty + j * 8, r = rb + tx;
        if (r < R && c < C) out[(size_t)c * R + r] = tile[tx][ty + j * 8];
    }
}

// ---------------------------------------------------------------------------
// CSR build: histogram -> exclusive scan -> scatter
// ---------------------------------------------------------------------------
__global__ __launch_bounds__(256) void k_hist(const int* __restrict__ rows,
                                              int* __restrict__ counts)
{
    int i = blockIdx.x * 256 + threadIdx.x;
    if (i < NNZ_N) atomicAdd(&counts[rows[i]], 1);
}

__global__ __launch_bounds__(1024) void k_scan(const int* __restrict__ counts,
                                               int* __restrict__ row_ptr,
                                               int* __restrict__ cursor)
{
    const int C = 20;  // 1024*20 = 20480 >= V_N
    __shared__ int sd[1024];
    int t = threadIdx.x;
    int beg = t * C;
    int end = beg + C; if (end > V_N) end = V_N;
    if (beg > V_N) beg = V_N;
    int s = 0;
    for (int i = beg; i < end; ++i) s += counts[i];
    sd[t] = s;
    __syncthreads();
    // Hillis-Steele inclusive scan over 1024 partials
    for (int off = 1; off < 1024; off <<= 1) {
        int add = (t >= off) ? sd[t - off] : 0;
        __syncthreads();
        sd[t] += add;
        __syncthreads();
    }
    int run = sd[t] - s;  // exclusive prefix of this thread's chunk
    for (int i = beg; i < end; ++i) {
        row_ptr[i] = run;
        cursor[i]  = run;
        run += counts[i];
    }
    if (t == 0) row_ptr[V_N] = NNZ_N;
}

__global__ __launch_bounds__(256) void k_scatter(const int* __restrict__ rows,
                                                 const int* __restrict__ cols_in,
                                                 const float* __restrict__ vals_in,
                                                 int* __restrict__ cursor,
                                                 int* __restrict__ csr_col,
                                                 float* __restrict__ csr_val)
{
    int i = blockIdx.x * 256 + threadIdx.x;
    if (i < NNZ_N) {
        int r = rows[i];
        int p = atomicAdd(&cursor[r], 1);
        csr_col[p] = cols_in[i];
        csr_val[p] = vals_in[i];
    }
}

// ---------------------------------------------------------------------------
// SpMM: dst[v,:] = sum_j val_j * src[col_j,:]     (cheb=0)
//       dst[v,:] = 2*sum_j val_j*src[col_j,:] - dst[v,:]   (cheb=1, in-place
//       elementwise over x_{k-2} -- safe: each thread RMWs only its own slot)
// grid (V_N, 2), block 256; each block covers 1024 features via float4.
// ---------------------------------------------------------------------------
__global__ __launch_bounds__(256) void k_spmm(const float* __restrict__ src,
                                              float* __restrict__ dst,
                                              const int* __restrict__ row_ptr,
                                              const int* __restrict__ csr_col,
                                              const float* __restrict__ csr_val,
                                              int cheb)
{
    int v = blockIdx.x;
    int f = blockIdx.y * 1024 + threadIdx.x * 4;
    int jb = row_ptr[v], je = row_ptr[v + 1];

    float ax = 0.f, ay = 0.f, az = 0.f, aw = 0.f;
    float bx = 0.f, by = 0.f, bz = 0.f, bw = 0.f;
    int j = jb;
    for (; j + 1 < je; j += 2) {
        int   c0 = csr_col[j],     c1 = csr_col[j + 1];
        float s0 = csr_val[j],     s1 = csr_val[j + 1];
        float4 x0 = *reinterpret_cast<const float4*>(src + (size_t)c0 * F_N + f);
        float4 x1 = *reinterpret_cast<const float4*>(src + (size_t)c1 * F_N + f);
        ax += s0 * x0.x; ay += s0 * x0.y; az += s0 * x0.z; aw += s0 * x0.w;
        bx += s1 * x1.x; by += s1 * x1.y; bz += s1 * x1.z; bw += s1 * x1.w;
    }
    if (j < je) {
        int   c0 = csr_col[j];
        float s0 = csr_val[j];
        float4 x0 = *reinterpret_cast<const float4*>(src + (size_t)c0 * F_N + f);
        ax += s0 * x0.x; ay += s0 * x0.y; az += s0 * x0.z; aw += s0 * x0.w;
    }
    ax += bx; ay += by; az += bz; aw += bw;

    float4* dp = reinterpret_cast<float4*>(dst + (size_t)v * F_N + f);
    if (cheb) {
        float4 old = *dp;
        ax = 2.f * ax - old.x;
        ay = 2.f * ay - old.y;
        az = 2.f * az - old.z;
        aw = 2.f * aw - old.w;
    }
    *dp = make_float4(ax, ay, az, aw);
}

// ---------------------------------------------------------------------------
// GEMM pass r:  oacc[v, b*128+o] (+)= sum_i A[v, b*128+i] * W[i*128+o]
// Tile: 8 v * 16 b = 128 rows x 128 cols, K=128 in chunks of 32.
// 256 threads, 8x8 register tile per thread. rflag==0 seeds with bias.
// ---------------------------------------------------------------------------
__global__ __launch_bounds__(256) void k_gemm_pass(const float* __restrict__ A,
                                                   const float* __restrict__ W,
                                                   const float* __restrict__ bias,
                                                   float* __restrict__ oacc,
                                                   int rflag)
{
    __shared__ __align__(16) float At[32][132];  // [k][vb], pad keeps b128 reads clean
    __shared__ __align__(16) float Wl[32][128];  // [k][o]

    int tid = threadIdx.x;
    int tx = tid & 15;        // -> o groups {tx*4..+3, 64+tx*4..+3}
    int ty = tid >> 4;        // -> rows ty*8 .. ty*8+7
    int v0 = blockIdx.x * 8;

    float c[8][8];
    if (rflag == 0) {
#pragma unroll
        for (int g = 0; g < 2; ++g) {
            float4 bv = *reinterpret_cast<const float4*>(bias + g * 64 + tx * 4);
#pragma unroll
            for (int rr = 0; rr < 8; ++rr) {
                c[rr][g * 4 + 0] = bv.x; c[rr][g * 4 + 1] = bv.y;
                c[rr][g * 4 + 2] = bv.z; c[rr][g * 4 + 3] = bv.w;
            }
        }
    } else {
#pragma unroll
        for (int rr = 0; rr < 8; ++rr) {
            int vb = ty * 8 + rr;
            int v = v0 + (vb >> 4), b = vb & 15;
            const float* op = oacc + (size_t)v * F_N + b * 128;
            float4 l0 = *reinterpret_cast<const float4*>(op + tx * 4);
            float4 l1 = *reinterpret_cast<const float4*>(op + 64 + tx * 4);
            c[rr][0] = l0.x; c[rr][1] = l0.y; c[rr][2] = l0.z; c[rr][3] = l0.w;
            c[rr][4] = l1.x; c[rr][5] = l1.y; c[rr][6] = l1.z; c[rr][7] = l1.w;
        }
    }

    for (int k0 = 0; k0 < 128; k0 += 32) {
        __syncthreads();
#pragma unroll
        for (int it = 0; it < 4; ++it) {
            int q  = it * 256 + tid;      // 0..1023
            int vb = q >> 3, k4 = q & 7;
            int v = v0 + (vb >> 4), b = vb & 15;
            float4 av = *reinterpret_cast<const float4*>(
                A + (size_t)v * F_N + b * 128 + k0 + k4 * 4);
            At[k4 * 4 + 0][vb] = av.x;
            At[k4 * 4 + 1][vb] = av.y;
            At[k4 * 4 + 2][vb] = av.z;
            At[k4 * 4 + 3][vb] = av.w;
            reinterpret_cast<float4*>(&Wl[0][0])[q] =
                reinterpret_cast<const float4*>(W + (size_t)k0 * 128)[q];
        }
        __syncthreads();
#pragma unroll
        for (int k = 0; k < 32; ++k) {
            float4 a0 = *reinterpret_cast<const float4*>(&At[k][ty * 8]);
            float4 a1 = *reinterpret_cast<const float4*>(&At[k][ty * 8 + 4]);
            float4 w0 = *reinterpret_cast<const float4*>(&Wl[k][tx * 4]);
            float4 w1 = *reinterpret_cast<const float4*>(&Wl[k][64 + tx * 4]);
            float a[8] = {a0.x, a0.y, a0.z, a0.w, a1.x, a1.y, a1.z, a1.w};
            float w[8] = {w0.x, w0.y, w0.z, w0.w, w1.x, w1.y, w1.z, w1.w};
#pragma unroll
            for (int rr = 0; rr < 8; ++rr)
#pragma unroll
                for (int oo = 0; oo < 8; ++oo)
                    c[rr][oo] += a[rr] * w[oo];
        }
    }

#pragma unroll
    for (int rr = 0; rr < 8; ++rr) {
        int vb = ty * 8 + rr;
        int v = v0 + (vb >> 4), b = vb & 15;
        float* op = oacc + (size_t)v * F_N + b * 128;
        *reinterpret_cast<float4*>(op + tx * 4) =
            make_float4(c[rr][0], c[rr][1], c[rr][2], c[rr][3]);
        *reinterpret_cast<float4*>(op + 64 + tx * 4) =
            make_float4(c[rr][4], c[rr][5], c[rr][6], c[rr][7]);
    }
}

// ---------------------------------------------------------------------------
extern "C" void kernel_launch(void* const* d_in, const int* in_sizes, int n_in,
                              void* d_out, int out_size, void* d_ws, size_t ws_size,
                              hipStream_t stream)
{
    const float* x        = (const float*)d_in[0];
    const float* weight   = (const float*)d_in[1];
    const float* bias     = (const float*)d_in[2];
    const float* lap_vals = (const float*)d_in[3];
    const int*   lap_rows = (const int*)d_in[4];
    const int*   lap_cols = (const int*)d_in[5];
    float* out = (float*)d_out;

    // workspace carve: p0, p1 (Chebyshev planes), oacc, CSR scratch  (~497 MB)
    size_t plane = (size_t)V_N * F_N;
    float* p0      = (float*)d_ws;
    float* p1      = p0 + plane;
    float* oacc    = p1 + plane;
    int*   counts  = (int*)(oacc + plane);
    int*   row_ptr = counts + V_N;
    int*   cursor  = row_ptr + V_N + 1;
    int*   csr_col = cursor + V_N;
    float* csr_val = (float*)(csr_col + NNZ_N);

    // --- CSR build (per launch; inputs restored pristine each call) ---
    hipMemsetAsync(counts, 0, V_N * sizeof(int), stream);
    k_hist<<<(NNZ_N + 255) / 256, 256, 0, stream>>>(lap_rows, counts);
    k_scan<<<1, 1024, 0, stream>>>(counts, row_ptr, cursor);
    k_scatter<<<(NNZ_N + 255) / 256, 256, 0, stream>>>(lap_rows, lap_cols, lap_vals,
                                                       cursor, csr_col, csr_val);

    // --- x0 = transpose(x): (2048, V) -> (V, 2048) ---
    k_transpose<<<dim3(V_N / 32, F_N / 32), dim3(32, 8), 0, stream>>>(x, p0, F_N, V_N);

    // --- r=0: oacc = bias + x0 @ W0 ---
    k_gemm_pass<<<V_N / 8, 256, 0, stream>>>(p0, weight, bias, oacc, 0);

    // --- x1 = L x0 ---
    k_spmm<<<dim3(V_N, 2), 256, 0, stream>>>(p0, p1, row_ptr, csr_col, csr_val, 0);
    k_gemm_pass<<<V_N / 8, 256, 0, stream>>>(p1, weight + 1 * 128 * 128, bias, oacc, 1);

    // --- x2 = 2 L x1 - x0   (in place over p0) ---
    k_spmm<<<dim3(V_N, 2), 256, 0, stream>>>(p1, p0, row_ptr, csr_col, csr_val, 1);
    k_gemm_pass<<<V_N / 8, 256, 0, stream>>>(p0, weight + 2 * 128 * 128, bias, oacc, 2);

    // --- x3 = 2 L x2 - x1   (in place over p1) ---
    k_spmm<<<dim3(V_N, 2), 256, 0, stream>>>(p0, p1, row_ptr, csr_col, csr_val, 1);
    k_gemm_pass<<<V_N / 8, 256, 0, stream>>>(p1, weight + 3 * 128 * 128, bias, oacc, 3);

    // --- out (B, Cout, V) = transpose(oacc): (V, 2048) -> (2048, V) ---
    k_transpose<<<dim3(F_N / 32, V_N / 32), dim3(32, 8), 0, stream>>>(oacc, out, V_N, F_N);
}

// Round 3
// 2091.794 us; speedup vs baseline: 1.5387x; 1.5387x over previous
//
#include <hip/hip_runtime.h>

#define V_N    20000
#define NNZ_N  640000
#define B_N    16
#define CIN_N  128
#define COUT_N 128
#define F_N    2048   // B*CIN = features per vertex

typedef unsigned int u32;
typedef unsigned short u16;

// bf16 helpers: storage is raw u16/u32 words; math is fp32.
__device__ __forceinline__ float bf_lo(u32 w) { return __uint_as_float(w << 16); }
__device__ __forceinline__ float bf_hi(u32 w) { return __uint_as_float(w & 0xffff0000u); }
__device__ __forceinline__ u16 f2bf(float f) {   // round-to-nearest-even
    u32 u = __float_as_uint(f);
    u += 0x7fffu + ((u >> 16) & 1u);
    return (u16)(u >> 16);
}
__device__ __forceinline__ u32 pack2(float a, float b) {
    return (u32)f2bf(a) | ((u32)f2bf(b) << 16);
}

// ---------------------------------------------------------------------------
// Transpose fp32 (R x C) -> bf16 (C x R)
// ---------------------------------------------------------------------------
__global__ __launch_bounds__(256) void k_transpose_f2h(const float* __restrict__ in,
                                                       u16* __restrict__ out,
                                                       int R, int C)
{
    __shared__ float tile[32][33];
    int cb = blockIdx.x * 32;
    int rb = blockIdx.y * 32;
    int tx = threadIdx.x, ty = threadIdx.y;
#pragma unroll
    for (int j = 0; j < 4; ++j) {
        int r = rb + ty + j * 8, c = cb + tx;
        if (r < R && c < C) tile[ty + j * 8][tx] = in[(size_t)r * C + c];
    }
    __syncthreads();
#pragma unroll
    for (int j = 0; j < 4; ++j) {
        int c = cb + ty + j * 8, r = rb + tx;
        if (r < R && c < C) out[(size_t)c * R + r] = f2bf(tile[tx][ty + j * 8]);
    }
}

// fp32 (R x C) -> fp32 (C x R)   (final output transpose)
__global__ __launch_bounds__(256) void k_transpose(const float* __restrict__ in,
                                                   float* __restrict__ out,
                                                   int R, int C)
{
    __shared__ float tile[32][33];
    int cb = blockIdx.x * 32;
    int rb = blockIdx.y * 32;
    int tx = threadIdx.x, ty = threadIdx.y;
#pragma unroll
    for (int j = 0; j < 4; ++j) {
        int r = rb + ty + j * 8, c = cb + tx;
        if (r < R && c < C) tile[ty + j * 8][tx] = in[(size_t)r * C + c];
    }
    __syncthreads();
#pragma unroll
    for (int j = 0; j < 4; ++j) {
        int c = cb + ty + j * 8, r = rb + tx;
        if (r < R && c < C) out[(size_t)c * R + r] = tile[tx][ty + j * 8];
    }
}

// ---------------------------------------------------------------------------
// CSR build: histogram -> scan -> scatter
// ---------------------------------------------------------------------------
__global__ __launch_bounds__(256) void k_hist(const int* __restrict__ rows,
                                              int* __restrict__ counts)
{
    int i = blockIdx.x * 256 + threadIdx.x;
    if (i < NNZ_N) atomicAdd(&counts[rows[i]], 1);
}

__global__ __launch_bounds__(1024) void k_scan(const int* __restrict__ counts,
                                               int* __restrict__ row_ptr,
                                               int* __restrict__ cursor)
{
    const int C = 20;
    __shared__ int sd[1024];
    int t = threadIdx.x;
    int beg = t * C;
    int end = beg + C; if (end > V_N) end = V_N;
    if (beg > V_N) beg = V_N;
    int s = 0;
    for (int i = beg; i < end; ++i) s += counts[i];
    sd[t] = s;
    __syncthreads();
    for (int off = 1; off < 1024; off <<= 1) {
        int add = (t >= off) ? sd[t - off] : 0;
        __syncthreads();
        sd[t] += add;
        __syncthreads();
    }
    int run = sd[t] - s;
    for (int i = beg; i < end; ++i) {
        row_ptr[i] = run;
        cursor[i]  = run;
        run += counts[i];
    }
    if (t == 0) row_ptr[V_N] = NNZ_N;
}

__global__ __launch_bounds__(256) void k_scatter(const int* __restrict__ rows,
                                                 const int* __restrict__ cols_in,
                                                 const float* __restrict__ vals_in,
                                                 int* __restrict__ cursor,
                                                 int* __restrict__ csr_col,
                                                 float* __restrict__ csr_val)
{
    int i = blockIdx.x * 256 + threadIdx.x;
    if (i < NNZ_N) {
        int r = rows[i];
        int p = atomicAdd(&cursor[r], 1);
        csr_col[p] = cols_in[i];
        csr_val[p] = vals_in[i];
    }
}

// ---------------------------------------------------------------------------
// SpMM over bf16 planes, fp32 accumulate.
//   cheb=0: dst[v,:] =     sum_j val_j * src[col_j,:]
//   cheb=1: dst[v,:] = 2 * sum_j val_j * src[col_j,:] - dst[v,:]  (in place)
// grid = V_N blocks x 256 threads; thread handles 8 features (16 B loads).
// cols/vals staged to LDS per 64-nnz chunk; gather loop unrolled x4.
// ---------------------------------------------------------------------------
__device__ __forceinline__ void acc8(float* acc, float s, uint4 q)
{
    acc[0] += s * bf_lo(q.x); acc[1] += s * bf_hi(q.x);
    acc[2] += s * bf_lo(q.y); acc[3] += s * bf_hi(q.y);
    acc[4] += s * bf_lo(q.z); acc[5] += s * bf_hi(q.z);
    acc[6] += s * bf_lo(q.w); acc[7] += s * bf_hi(q.w);
}

__global__ __launch_bounds__(256) void k_spmm_h(const u16* __restrict__ src,
                                                u16* __restrict__ dst,
                                                const int* __restrict__ row_ptr,
                                                const int* __restrict__ csr_col,
                                                const float* __restrict__ csr_val,
                                                int cheb)
{
    __shared__ int   scol[64];
    __shared__ float sval[64];

    int v = blockIdx.x;
    int tid = threadIdx.x;
    int jb = row_ptr[v], je = row_ptr[v + 1];
    size_t fo = (size_t)tid * 8;

    float acc[8] = {0.f, 0.f, 0.f, 0.f, 0.f, 0.f, 0.f, 0.f};

    for (int j0 = jb; j0 < je; j0 += 64) {
        int n = je - j0; if (n > 64) n = 64;
        __syncthreads();
        if (tid < n) { scol[tid] = csr_col[j0 + tid]; sval[tid] = csr_val[j0 + tid]; }
        __syncthreads();
        int i = 0;
        for (; i + 3 < n; i += 4) {
            int   c0 = scol[i],     c1 = scol[i + 1], c2 = scol[i + 2], c3 = scol[i + 3];
            float s0 = sval[i],     s1 = sval[i + 1], s2 = sval[i + 2], s3 = sval[i + 3];
            uint4 q0 = *reinterpret_cast<const uint4*>(src + (size_t)c0 * F_N + fo);
            uint4 q1 = *reinterpret_cast<const uint4*>(src + (size_t)c1 * F_N + fo);
            uint4 q2 = *reinterpret_cast<const uint4*>(src + (size_t)c2 * F_N + fo);
            uint4 q3 = *reinterpret_cast<const uint4*>(src + (size_t)c3 * F_N + fo);
            acc8(acc, s0, q0); acc8(acc, s1, q1); acc8(acc, s2, q2); acc8(acc, s3, q3);
        }
        for (; i < n; ++i) {
            int   c0 = scol[i];
            float s0 = sval[i];
            uint4 q0 = *reinterpret_cast<const uint4*>(src + (size_t)c0 * F_N + fo);
            acc8(acc, s0, q0);
        }
    }

    u16* dp = dst + (size_t)v * F_N + fo;
    if (cheb) {
        uint4 oldq = *reinterpret_cast<const uint4*>(dp);
        float old[8];
        old[0] = bf_lo(oldq.x); old[1] = bf_hi(oldq.x);
        old[2] = bf_lo(oldq.y); old[3] = bf_hi(oldq.y);
        old[4] = bf_lo(oldq.z); old[5] = bf_hi(oldq.z);
        old[6] = bf_lo(oldq.w); old[7] = bf_hi(oldq.w);
#pragma unroll
        for (int t = 0; t < 8; ++t) acc[t] = 2.f * acc[t] - old[t];
    }
    uint4 o;
    o.x = pack2(acc[0], acc[1]);
    o.y = pack2(acc[2], acc[3]);
    o.z = pack2(acc[4], acc[5]);
    o.w = pack2(acc[6], acc[7]);
    *reinterpret_cast<uint4*>(dp) = o;
}

// ---------------------------------------------------------------------------
// GEMM pass r: oacc[v, b*128+o] (+)= sum_i A[v, b*128+i] * W[i*128+o]
// A is bf16; LDS/compute fp32. 128x128 tile, K in chunks of 32, 8x8/thread.
// ---------------------------------------------------------------------------
__global__ __launch_bounds__(256) void k_gemm_pass(const u16* __restrict__ A,
                                                   const float* __restrict__ W,
                                                   const float* __restrict__ bias,
                                                   float* __restrict__ oacc,
                                                   int rflag)
{
    __shared__ __align__(16) float At[32][132];
    __shared__ __align__(16) float Wl[32][128];

    int tid = threadIdx.x;
    int tx = tid & 15;
    int ty = tid >> 4;
    int v0 = blockIdx.x * 8;

    float c[8][8];
    if (rflag == 0) {
#pragma unroll
        for (int g = 0; g < 2; ++g) {
            float4 bv = *reinterpret_cast<const float4*>(bias + g * 64 + tx * 4);
#pragma unroll
            for (int rr = 0; rr < 8; ++rr) {
                c[rr][g * 4 + 0] = bv.x; c[rr][g * 4 + 1] = bv.y;
                c[rr][g * 4 + 2] = bv.z; c[rr][g * 4 + 3] = bv.w;
            }
        }
    } else {
#pragma unroll
        for (int rr = 0; rr < 8; ++rr) {
            int vb = ty * 8 + rr;
            int v = v0 + (vb >> 4), b = vb & 15;
            const float* op = oacc + (size_t)v * F_N + b * 128;
            float4 l0 = *reinterpret_cast<const float4*>(op + tx * 4);
            float4 l1 = *reinterpret_cast<const float4*>(op + 64 + tx * 4);
            c[rr][0] = l0.x; c[rr][1] = l0.y; c[rr][2] = l0.z; c[rr][3] = l0.w;
            c[rr][4] = l1.x; c[rr][5] = l1.y; c[rr][6] = l1.z; c[rr][7] = l1.w;
        }
    }

    for (int k0 = 0; k0 < 128; k0 += 32) {
        __syncthreads();
        // stage A (bf16 -> fp32): 512 loads of 8 bf16
#pragma unroll
        for (int it = 0; it < 2; ++it) {
            int idx = it * 256 + tid;       // 0..511
            int k8 = idx >> 7;              // 0..3
            int vb = idx & 127;             // 0..127
            int v = v0 + (vb >> 4), b = vb & 15;
            uint4 q = *reinterpret_cast<const uint4*>(
                A + (size_t)v * F_N + b * 128 + k0 + k8 * 8);
            float f[8];
            f[0] = bf_lo(q.x); f[1] = bf_hi(q.x);
            f[2] = bf_lo(q.y); f[3] = bf_hi(q.y);
            f[4] = bf_lo(q.z); f[5] = bf_hi(q.z);
            f[6] = bf_lo(q.w); f[7] = bf_hi(q.w);
#pragma unroll
            for (int t = 0; t < 8; ++t) At[k8 * 8 + t][vb] = f[t];
        }
        // stage W (fp32)
#pragma unroll
        for (int it = 0; it < 4; ++it) {
            int q = it * 256 + tid;         // 0..1023
            reinterpret_cast<float4*>(&Wl[0][0])[q] =
                reinterpret_cast<const float4*>(W + (size_t)k0 * 128)[q];
        }
        __syncthreads();
#pragma unroll
        for (int k = 0; k < 32; ++k) {
            float4 a0 = *reinterpret_cast<const float4*>(&At[k][ty * 8]);
            float4 a1 = *reinterpret_cast<const float4*>(&At[k][ty * 8 + 4]);
            float4 w0 = *reinterpret_cast<const float4*>(&Wl[k][tx * 4]);
            float4 w1 = *reinterpret_cast<const float4*>(&Wl[k][64 + tx * 4]);
            float a[8] = {a0.x, a0.y, a0.z, a0.w, a1.x, a1.y, a1.z, a1.w};
            float w[8] = {w0.x, w0.y, w0.z, w0.w, w1.x, w1.y, w1.z, w1.w};
#pragma unroll
            for (int rr = 0; rr < 8; ++rr)
#pragma unroll
                for (int oo = 0; oo < 8; ++oo)
                    c[rr][oo] += a[rr] * w[oo];
        }
    }

#pragma unroll
    for (int rr = 0; rr < 8; ++rr) {
        int vb = ty * 8 + rr;
        int v = v0 + (vb >> 4), b = vb & 15;
        float* op = oacc + (size_t)v * F_N + b * 128;
        *reinterpret_cast<float4*>(op + tx * 4) =
            make_float4(c[rr][0], c[rr][1], c[rr][2], c[rr][3]);
        *reinterpret_cast<float4*>(op + 64 + tx * 4) =
            make_float4(c[rr][4], c[rr][5], c[rr][6], c[rr][7]);
    }
}

// ---------------------------------------------------------------------------
extern "C" void kernel_launch(void* const* d_in, const int* in_sizes, int n_in,
                              void* d_out, int out_size, void* d_ws, size_t ws_size,
                              hipStream_t stream)
{
    const float* x        = (const float*)d_in[0];
    const float* weight   = (const float*)d_in[1];
    const float* bias     = (const float*)d_in[2];
    const float* lap_vals = (const float*)d_in[3];
    const int*   lap_rows = (const int*)d_in[4];
    const int*   lap_cols = (const int*)d_in[5];
    float* out = (float*)d_out;

    // workspace: h0, h1 (bf16 planes), oacc (fp32), CSR scratch  (~336 MB)
    size_t plane = (size_t)V_N * F_N;
    u16*   h0 = (u16*)d_ws;
    u16*   h1 = h0 + plane;
    float* oacc    = (float*)(h1 + plane);
    int*   counts  = (int*)(oacc + plane);
    int*   row_ptr = counts + V_N;
    int*   cursor  = row_ptr + V_N + 1;
    int*   csr_col = cursor + V_N;
    float* csr_val = (float*)(csr_col + NNZ_N);

    // --- CSR build ---
    (void)hipMemsetAsync(counts, 0, V_N * sizeof(int), stream);
    k_hist<<<(NNZ_N + 255) / 256, 256, 0, stream>>>(lap_rows, counts);
    k_scan<<<1, 1024, 0, stream>>>(counts, row_ptr, cursor);
    k_scatter<<<(NNZ_N + 255) / 256, 256, 0, stream>>>(lap_rows, lap_cols, lap_vals,
                                                       cursor, csr_col, csr_val);

    // --- h0 = bf16(transpose(x)) : (2048, V) -> (V, 2048) ---
    k_transpose_f2h<<<dim3(V_N / 32, F_N / 32), dim3(32, 8), 0, stream>>>(x, h0, F_N, V_N);

    // --- r=0: oacc = bias + x0 @ W0 ---
    k_gemm_pass<<<V_N / 8, 256, 0, stream>>>(h0, weight, bias, oacc, 0);

    // --- x1 = L x0 ---
    k_spmm_h<<<V_N, 256, 0, stream>>>(h0, h1, row_ptr, csr_col, csr_val, 0);
    k_gemm_pass<<<V_N / 8, 256, 0, stream>>>(h1, weight + 1 * 128 * 128, bias, oacc, 1);

    // --- x2 = 2 L x1 - x0   (in place over h0) ---
    k_spmm_h<<<V_N, 256, 0, stream>>>(h1, h0, row_ptr, csr_col, csr_val, 1);
    k_gemm_pass<<<V_N / 8, 256, 0, stream>>>(h0, weight + 2 * 128 * 128, bias, oacc, 2);

    // --- x3 = 2 L x2 - x1   (in place over h1) ---
    k_spmm_h<<<V_N, 256, 0, stream>>>(h0, h1, row_ptr, csr_col, csr_val, 1);
    k_gemm_pass<<<V_N / 8, 256, 0, stream>>>(h1, weight + 3 * 128 * 128, bias, oacc, 3);

    // --- out (B, Cout, V) = transpose(oacc) ---
    k_transpose<<<dim3(F_N / 32, V_N / 32), dim3(32, 8), 0, stream>>>(oacc, out, V_N, F_N);
}